// Round 7
// baseline (357.898 us; speedup 1.0000x reference)
//
#include <hip/hip_runtime.h>
#include <hip/hip_bf16.h>
#include <hip/hip_cooperative_groups.h>

namespace cg = cooperative_groups;

constexpr int B_  = 8;
constexpr int S_  = 512;
constexpr int V_  = 30522;
constexpr int V2_ = V_ / 2;                      // 15261 float2 per row
constexpr int V4_ = V_ / 4;                      // 7630 full float4 per row (+1 float2 tail)

// Fused cooperative kernel: 256 blocks x 1024 threads (1 block/CU co-resident).
// Phase 1: masked partial max-pool (float4 row-streaming), tiles (vs,g,b) 1:1 blocks.
// Phase 2: wide merge of NS partials -> out.
// Phase 3: blocks 0..7 do per-row exact top-k threshold + log1p finalize.
constexpr int NTHREADS = 1024;
constexpr int VSPLIT   = 4;
constexpr int SLICE4   = 1908;                   // float4 per slice (slice 3: 1906 + tail)
constexpr int NS       = 8;                      // row groups: 4*8*8 = 256 tiles = grid
constexpr int NBLOCKS  = VSPLIT * NS * B_;       // 256
constexpr int NSLOT    = 2;                      // 2 float4 per thread

constexpr int NPT2 = (V2_ + NTHREADS - 1) / NTHREADS;   // 15 float2 -> 30 uints

__global__ __launch_bounds__(NTHREADS, 4)
void splade_fused(const float* __restrict__ logits,
                  const int* __restrict__ mask,
                  const int* __restrict__ topk_ptr,
                  float* __restrict__ out,
                  float* __restrict__ partial)   // [NS][B][V_] in ws
{
    cg::grid_group grid = cg::this_grid();

    __shared__ int s_idx[S_];
    __shared__ int s_cnt;
    __shared__ int s_hist[32];

    // ---------------- Phase 1: masked partial max ----------------
    {
        const int tile = blockIdx.x;
        const int vs = tile & 3;
        const int g  = (tile >> 2) & (NS - 1);
        const int b  = tile >> 5;

        // Wave 0 compacts active row indices via ballot prefix (no LDS atomics).
        if (threadIdx.x < 64) {
            const int lane = threadIdx.x;
            int cnt = 0;
            for (int base = 0; base < S_; base += 64) {
                const int m = mask[b * S_ + base + lane] != 0;
                const unsigned long long bal = __ballot(m);
                if (m) s_idx[cnt + (int)__popcll(bal & ((1ull << lane) - 1ull))] = base + lane;
                cnt += (int)__popcll(bal);
            }
            if (lane == 0) s_cnt = cnt;
        }
        __syncthreads();
        const int n = s_cnt;

        const int len4 = (vs == VSPLIT - 1) ? (V4_ - vs * SLICE4) : SLICE4;  // 1908/1906
        int  col4[NSLOT];
        bool valid[NSLOT];
#pragma unroll
        for (int p = 0; p < NSLOT; ++p) {
            const int idx4 = threadIdx.x + p * NTHREADS;
            valid[p] = (idx4 < len4);
            col4[p]  = valid[p] ? (vs * SLICE4 + idx4) : 0;   // clamp -> broadcast line
        }

        float4 acc[NSLOT];
#pragma unroll
        for (int p = 0; p < NSLOT; ++p) acc[p] = make_float4(0.f, 0.f, 0.f, 0.f);

        const bool do_tail = (vs == VSPLIT - 1) && (threadIdx.x == 0);
        float2 acc_t = make_float2(0.f, 0.f);

        int r = g;
        for (; r + NS < n; r += 2 * NS) {                    // 2-row pipeline
            const int s0 = s_idx[r], s1 = s_idx[r + NS];
            const float* r0 = logits + (size_t)(b * S_ + s0) * V_;
            const float* r1 = logits + (size_t)(b * S_ + s1) * V_;
            float4 x0[NSLOT], x1[NSLOT];
#pragma unroll
            for (int p = 0; p < NSLOT; ++p)
                x0[p] = *reinterpret_cast<const float4*>(r0 + 4 * col4[p]);
#pragma unroll
            for (int p = 0; p < NSLOT; ++p)
                x1[p] = *reinterpret_cast<const float4*>(r1 + 4 * col4[p]);
            if (do_tail) {
                const float2 t0 = *reinterpret_cast<const float2*>(r0 + 2 * (V2_ - 1));
                const float2 t1 = *reinterpret_cast<const float2*>(r1 + 2 * (V2_ - 1));
                acc_t.x = fmaxf(acc_t.x, fmaxf(t0.x, t1.x));
                acc_t.y = fmaxf(acc_t.y, fmaxf(t0.y, t1.y));
            }
#pragma unroll
            for (int p = 0; p < NSLOT; ++p) {
                acc[p].x = fmaxf(acc[p].x, fmaxf(x0[p].x, x1[p].x));
                acc[p].y = fmaxf(acc[p].y, fmaxf(x0[p].y, x1[p].y));
                acc[p].z = fmaxf(acc[p].z, fmaxf(x0[p].z, x1[p].z));
                acc[p].w = fmaxf(acc[p].w, fmaxf(x0[p].w, x1[p].w));
            }
        }
        if (r < n) {                                         // odd tail row
            const float* r0 = logits + (size_t)(b * S_ + s_idx[r]) * V_;
            float4 x0[NSLOT];
#pragma unroll
            for (int p = 0; p < NSLOT; ++p)
                x0[p] = *reinterpret_cast<const float4*>(r0 + 4 * col4[p]);
            if (do_tail) {
                const float2 t0 = *reinterpret_cast<const float2*>(r0 + 2 * (V2_ - 1));
                acc_t.x = fmaxf(acc_t.x, t0.x);
                acc_t.y = fmaxf(acc_t.y, t0.y);
            }
#pragma unroll
            for (int p = 0; p < NSLOT; ++p) {
                acc[p].x = fmaxf(acc[p].x, x0[p].x);
                acc[p].y = fmaxf(acc[p].y, x0[p].y);
                acc[p].z = fmaxf(acc[p].z, x0[p].z);
                acc[p].w = fmaxf(acc[p].w, x0[p].w);
            }
        }

        float* dst = partial + ((size_t)g * B_ + b) * V_;
#pragma unroll
        for (int p = 0; p < NSLOT; ++p)
            if (valid[p])
                *reinterpret_cast<float4*>(dst + 4 * col4[p]) = acc[p];
        if (do_tail)
            *reinterpret_cast<float2*>(dst + 2 * (V2_ - 1)) = acc_t;
    }

    __threadfence();            // device-scope release (cross-XCD visibility)
    grid.sync();

    // ---------------- Phase 2: wide merge of NS partials -> out ----------------
    {
        const int tid = blockIdx.x * NTHREADS + threadIdx.x;
        if (tid < B_ * V2_) {
            const int b    = tid / V2_;
            const int idx2 = tid - b * V2_;
            const float2* p0 = reinterpret_cast<const float2*>(partial)
                               + (size_t)b * V2_ + idx2;
            float2 m = make_float2(0.0f, 0.0f);
#pragma unroll
            for (int gg = 0; gg < NS; ++gg) {
                const float2 x = p0[(size_t)gg * B_ * V2_];
                m.x = fmaxf(m.x, x.x);
                m.y = fmaxf(m.y, x.y);
            }
            reinterpret_cast<float2*>(out)[(size_t)b * V2_ + idx2] = m;
        }
    }

    __threadfence();
    grid.sync();

    // ---------------- Phase 3: per-row exact top-k + finalize (blocks 0..7) -------
    if (blockIdx.x >= B_) return;
    {
        const int b = blockIdx.x;
        const int k = topk_ptr[0];
        float2* row2 = reinterpret_cast<float2*>(out) + (size_t)b * V2_;

        unsigned int v[2 * NPT2];        // register cache, static indexing only
#pragma unroll
        for (int i = 0; i < NPT2; ++i) {
            const int idx2 = threadIdx.x + i * NTHREADS;
            float2 x = make_float2(0.0f, 0.0f);          // OOB zeros never counted
            if (idx2 < V2_) x = row2[idx2];
            v[2 * i]     = __float_as_uint(x.x);
            v[2 * i + 1] = __float_as_uint(x.y);
        }

        for (int i = threadIdx.x; i < 32; i += NTHREADS) s_hist[i] = 0;
        __syncthreads();

        // invariant: count(bits >= lo) >= k,  count(bits >= hi) < k
        unsigned int lo = 0u, hi = 0x7f800000u;
        for (int it = 0; it < 32; ++it) {
            if (hi - lo <= 1u) break;                    // uniform across block
            const unsigned int mid = lo + ((hi - lo) >> 1);  // mid >= 1
            int c = 0;
#pragma unroll
            for (int i = 0; i < 2 * NPT2; ++i)
                c += (int)__popcll(__ballot(v[i] >= mid));   // wave-uniform count
            if ((threadIdx.x & 63) == 0) atomicAdd(&s_hist[it], c);
            __syncthreads();                             // the ONLY barrier per step
            const int cnt = s_hist[it];
            if (cnt >= k) lo = mid; else hi = mid;
        }

        const unsigned int T = lo;       // exactly the k-th largest value's bits
#pragma unroll
        for (int i = 0; i < NPT2; ++i) {
            const int idx2 = threadIdx.x + i * NTHREADS;
            if (idx2 < V2_) {
                const unsigned int a = v[2 * i], c = v[2 * i + 1];
                float rx = 0.0f, ry = 0.0f;
                if (a >= T) rx = log1pf(__uint_as_float(a));
                if (c >= T) ry = log1pf(__uint_as_float(c));
                row2[idx2] = make_float2(rx, ry);
            }
        }
    }
}

extern "C" void kernel_launch(void* const* d_in, const int* in_sizes, int n_in,
                              void* d_out, int out_size, void* d_ws, size_t ws_size,
                              hipStream_t stream) {
    const float* logits = (const float*)d_in[0];
    const int*   mask   = (const int*)d_in[1];
    const int*   topk   = (const int*)d_in[2];
    float*       out    = (float*)d_out;
    float*       ws     = (float*)d_ws;   // needs NS*B*V*4 = 7.8 MB of scratch

    void* args[] = { (void*)&logits, (void*)&mask, (void*)&topk,
                     (void*)&out, (void*)&ws };
    hipLaunchCooperativeKernel((const void*)splade_fused,
                               dim3(NBLOCKS), dim3(NTHREADS),
                               args, 0, stream);
}

// Round 8
// 90.130 us; speedup vs baseline: 3.9709x; 3.9709x over previous
//
#include <hip/hip_runtime.h>
#include <hip/hip_bf16.h>

constexpr int B_  = 8;
constexpr int S_  = 512;
constexpr int V_  = 30522;
constexpr int V2_ = V_ / 2;                      // 15261 float2 per row
constexpr int V4_ = V_ / 4;                      // 7630 full float4 per row (+1 float2 tail)

typedef float f32x4 __attribute__((ext_vector_type(4)));
typedef float f32x2 __attribute__((ext_vector_type(2)));

// Nontemporal loads: logits are streamed once per call; testing whether the nt
// bit lifts the cached-read path (L2 no-allocate) without losing L3 retention.
static __device__ __forceinline__ f32x4 ntload4(const float* p) {
    return __builtin_nontemporal_load(reinterpret_cast<const f32x4*>(p));
}
static __device__ __forceinline__ f32x2 ntload2(const float* p) {
    return __builtin_nontemporal_load(reinterpret_cast<const f32x2*>(p));
}

// ---------------- Kernel 1: masked partial max-pool, float4 row-streaming ---------
// Block (vs, g, b) streams contiguous ~30.5 KB float4 slices of every active row in
// group g (compacted rows g, g+NS, ...), running max in registers.
constexpr int K1_THREADS = 1024;
constexpr int VSPLIT  = 4;
constexpr int SLICE4  = 1908;                    // float4 per slice (slice 3: 1906 + tail)
constexpr int NS      = 16;                      // row groups -> 512 blocks total
constexpr int NSLOT   = 2;                       // 2 float4 per thread (2048 slots >= 1908)

__global__ __launch_bounds__(K1_THREADS)
void splade_partial_max(const float* __restrict__ logits,
                        const int* __restrict__ mask,
                        float* __restrict__ partial)     // [NS][B][V_] in ws
{
    __shared__ int s_idx[S_];
    __shared__ int s_cnt;
    const int vs = blockIdx.x;
    const int g  = blockIdx.y;
    const int b  = blockIdx.z;

    // Wave 0 compacts active row indices via ballot prefix (no LDS atomics).
    if (threadIdx.x < 64) {
        const int lane = threadIdx.x;
        int cnt = 0;
        for (int base = 0; base < S_; base += 64) {
            const int m = mask[b * S_ + base + lane] != 0;
            const unsigned long long bal = __ballot(m);
            if (m) s_idx[cnt + (int)__popcll(bal & ((1ull << lane) - 1ull))] = base + lane;
            cnt += (int)__popcll(bal);
        }
        if (lane == 0) s_cnt = cnt;
    }
    __syncthreads();
    const int n = s_cnt;

    // Per-slot float4 column index within the row. Invalid slots clamp to col 0
    // (single broadcast cache line -> negligible) and are skipped on store.
    const int len4 = (vs == VSPLIT - 1) ? (V4_ - vs * SLICE4) : SLICE4;  // 1908 / 1906
    int  col4[NSLOT];
    bool valid[NSLOT];
#pragma unroll
    for (int p = 0; p < NSLOT; ++p) {
        const int idx4 = threadIdx.x + p * K1_THREADS;
        valid[p] = (idx4 < len4);
        col4[p]  = valid[p] ? (vs * SLICE4 + idx4) : 0;
    }

    f32x4 acc[NSLOT];
#pragma unroll
    for (int p = 0; p < NSLOT; ++p) acc[p] = (f32x4)(0.f);

    // One thread in the last slice owns the per-row trailing float2 (V % 4 == 2).
    const bool do_tail = (vs == VSPLIT - 1) && (threadIdx.x == 0);
    f32x2 acc_t = (f32x2)(0.f);

    int r = g;
    for (; r + NS < n; r += 2 * NS) {                    // 2-row pipeline
        const int s0 = s_idx[r], s1 = s_idx[r + NS];
        const float* r0 = logits + (size_t)(b * S_ + s0) * V_;
        const float* r1 = logits + (size_t)(b * S_ + s1) * V_;
        f32x4 x0[NSLOT], x1[NSLOT];
#pragma unroll
        for (int p = 0; p < NSLOT; ++p) x0[p] = ntload4(r0 + 4 * col4[p]);
#pragma unroll
        for (int p = 0; p < NSLOT; ++p) x1[p] = ntload4(r1 + 4 * col4[p]);
        if (do_tail) {
            const f32x2 t0 = ntload2(r0 + 2 * (V2_ - 1));
            const f32x2 t1 = ntload2(r1 + 2 * (V2_ - 1));
            acc_t[0] = fmaxf(acc_t[0], fmaxf(t0[0], t1[0]));
            acc_t[1] = fmaxf(acc_t[1], fmaxf(t0[1], t1[1]));
        }
#pragma unroll
        for (int p = 0; p < NSLOT; ++p) {
#pragma unroll
            for (int q = 0; q < 4; ++q)
                acc[p][q] = fmaxf(acc[p][q], fmaxf(x0[p][q], x1[p][q]));
        }
    }
    if (r < n) {                                         // odd tail row
        const float* r0 = logits + (size_t)(b * S_ + s_idx[r]) * V_;
        f32x4 x0[NSLOT];
#pragma unroll
        for (int p = 0; p < NSLOT; ++p) x0[p] = ntload4(r0 + 4 * col4[p]);
        if (do_tail) {
            const f32x2 t0 = ntload2(r0 + 2 * (V2_ - 1));
            acc_t[0] = fmaxf(acc_t[0], t0[0]);
            acc_t[1] = fmaxf(acc_t[1], t0[1]);
        }
#pragma unroll
        for (int p = 0; p < NSLOT; ++p) {
#pragma unroll
            for (int q = 0; q < 4; ++q)
                acc[p][q] = fmaxf(acc[p][q], x0[p][q]);
        }
    }

    float* dst = partial + ((size_t)g * B_ + b) * V_;    // cached stores (merge re-reads)
#pragma unroll
    for (int p = 0; p < NSLOT; ++p)
        if (valid[p])
            *reinterpret_cast<f32x4*>(dst + 4 * col4[p]) = acc[p];
    if (do_tail)
        *reinterpret_cast<f32x2*>(dst + 2 * (V2_ - 1)) = acc_t;
}

// ---------------- Kernel M: WIDE merge of NS partials -> out ----------------
// 480 blocks; k2 must never read the 15.6 MB of partials (8-CU bandwidth trap).
constexpr int KM_THREADS  = 256;
constexpr int KM_BLOCKS_X = (V2_ + KM_THREADS - 1) / KM_THREADS;   // 60

__global__ __launch_bounds__(KM_THREADS)
void splade_merge(const float* __restrict__ partial, float* __restrict__ out)
{
    const int b    = blockIdx.y;
    const int idx2 = blockIdx.x * KM_THREADS + threadIdx.x;
    if (idx2 >= V2_) return;
    const float2* p0 = reinterpret_cast<const float2*>(partial) + (size_t)b * V2_ + idx2;
    float2 m = make_float2(0.0f, 0.0f);
#pragma unroll
    for (int gg = 0; gg < NS; ++gg) {
        const float2 x = p0[(size_t)gg * B_ * V2_];
        m.x = fmaxf(m.x, x.x);
        m.y = fmaxf(m.y, x.y);
    }
    reinterpret_cast<float2*>(out)[(size_t)b * V2_ + idx2] = m;
}

// ---------------- Kernel 2: per-row exact top-k threshold + finalize ----------------
// One 1024-thread block per batch row; reads ONLY the final 1 MB (float2 loads).
// k-th largest (ties counted, = top_values[...,-1]) via binary search on the uint
// bit pattern; ballot+popc counts, one barrier per step.
constexpr int K2_BLOCK = 1024;
constexpr int NPT2 = (V2_ + K2_BLOCK - 1) / K2_BLOCK;    // 15 float2 -> 30 uints

__global__ __launch_bounds__(K2_BLOCK)
void splade_topk_kernel(float* __restrict__ out,
                        const int* __restrict__ topk_ptr)
{
    const int b = blockIdx.x;
    const int k = topk_ptr[0];
    float2* row2 = reinterpret_cast<float2*>(out) + (size_t)b * V2_;

    unsigned int v[2 * NPT2];            // register cache, static indexing only
#pragma unroll
    for (int i = 0; i < NPT2; ++i) {
        const int idx2 = threadIdx.x + i * K2_BLOCK;
        float2 x = make_float2(0.0f, 0.0f);              // OOB zeros never counted
        if (idx2 < V2_) x = row2[idx2];
        v[2 * i]     = __float_as_uint(x.x);
        v[2 * i + 1] = __float_as_uint(x.y);
    }

    __shared__ int s_cnt[32];
    for (int i = threadIdx.x; i < 32; i += K2_BLOCK) s_cnt[i] = 0;
    __syncthreads();

    // invariant: count(bits >= lo) >= k,  count(bits >= hi) < k
    unsigned int lo = 0u, hi = 0x7f800000u;
    for (int it = 0; it < 32; ++it) {
        if (hi - lo <= 1u) break;                        // uniform across block
        const unsigned int mid = lo + ((hi - lo) >> 1);  // mid >= 1
        int c = 0;
#pragma unroll
        for (int i = 0; i < 2 * NPT2; ++i)
            c += (int)__popcll(__ballot(v[i] >= mid));   // wave-uniform count
        if ((threadIdx.x & 63) == 0) atomicAdd(&s_cnt[it], c);
        __syncthreads();                                 // the ONLY barrier per step
        const int cnt = s_cnt[it];
        if (cnt >= k) lo = mid; else hi = mid;
    }

    const unsigned int T = lo;           // exactly the k-th largest value's bits
#pragma unroll
    for (int i = 0; i < NPT2; ++i) {
        const int idx2 = threadIdx.x + i * K2_BLOCK;
        if (idx2 < V2_) {
            const unsigned int a = v[2 * i], c = v[2 * i + 1];
            float rx = 0.0f, ry = 0.0f;
            if (a >= T) rx = log1pf(__uint_as_float(a));
            if (c >= T) ry = log1pf(__uint_as_float(c));
            row2[idx2] = make_float2(rx, ry);
        }
    }
}

extern "C" void kernel_launch(void* const* d_in, const int* in_sizes, int n_in,
                              void* d_out, int out_size, void* d_ws, size_t ws_size,
                              hipStream_t stream) {
    const float* logits = (const float*)d_in[0];
    const int*   mask   = (const int*)d_in[1];
    const int*   topk   = (const int*)d_in[2];
    float*       out    = (float*)d_out;
    float*       ws     = (float*)d_ws;   // needs NS*B*V*4 = 15.6 MB of scratch

    dim3 g1(VSPLIT, NS, B_);
    splade_partial_max<<<g1, K1_THREADS, 0, stream>>>(logits, mask, ws);
    dim3 gm(KM_BLOCKS_X, B_);
    splade_merge<<<gm, KM_THREADS, 0, stream>>>(ws, out);
    splade_topk_kernel<<<B_, K2_BLOCK, 0, stream>>>(out, topk);
}